// Round 6
// baseline (159.467 us; speedup 1.0000x reference)
//
#include <hip/hip_runtime.h>
#include <math.h>
#include <stdint.h>

#define B_ 4
#define T_ 64000
#define H_ 96
#define NCHUNK 250
#define TWO_PI_D 6.283185307179586

typedef float2 cplx;
__device__ __forceinline__ cplx cadd(cplx a, cplx b){ return make_float2(a.x+b.x, a.y+b.y); }
__device__ __forceinline__ cplx csub(cplx a, cplx b){ return make_float2(a.x-b.x, a.y-b.y); }
__device__ __forceinline__ cplx cmul(cplx a, cplx b){ return make_float2(a.x*b.x - a.y*b.y, a.x*b.y + a.y*b.x); }

// ---------------- static scratch ----------------
__device__ double g_f0vd[B_*T_];
__device__ float  g_fmod[B_*T_];
__device__ float  g_signal[B_*T_];
__device__ float  g_noise[B_*T_];
__device__ float  g_shaped[B_*T_];
__device__ float2 g_W1[B_*512*125];
__device__ float2 g_Z[B_*125*512];
__device__ double g_chunksum[B_*NCHUNK];
__device__ double g_chunkoff[B_*NCHUNK];
__device__ float  g_Kcomb[B_*132];
__device__ double g_stats[B_*2];

// ---------------- phase increment in f64 ----------------
__device__ __forceinline__ double dphase_at(const float* __restrict__ f0,
                                            const float* __restrict__ vr,
                                            const float* __restrict__ vd,
                                            int idx, int t, double* f0v_out){
  double tt = (double)t / 44100.0;
  double sv = sin(TWO_PI_D * (double)vr[idx] * tt);
  double vf = exp2((double)vd[idx] / 12.0);
  double lm = log(vf);
  double vm = exp(sv * lm);
  double f0s = (double)f0[idx];
  double f0v = (f0s > 0.0) ? f0s * vm : f0s;
  *f0v_out = f0v;
  return TWO_PI_D * f0v / 44100.0;
}

__global__ __launch_bounds__(256) void k_chunksum(const float* __restrict__ f0, const float* __restrict__ vr,
                                                  const float* __restrict__ vd){
  int b = blockIdx.x / NCHUNK, c = blockIdx.x % NCHUNK;
  int tid = threadIdx.x;
  int t = c*256 + tid;
  int idx = b*T_ + t;
  double f0v;
  double v = dphase_at(f0, vr, vd, idx, t, &f0v);
  for (int o=1;o<64;o<<=1) v += __shfl_down(v, o);
  __shared__ double wsum[4];
  int lane = tid & 63, wid = tid >> 6;
  if (lane == 0) wsum[wid] = v;
  __syncthreads();
  if (tid == 0) g_chunksum[b*NCHUNK + c] = wsum[0]+wsum[1]+wsum[2]+wsum[3];
}

__global__ __launch_bounds__(256) void k_scanchunks(const float* __restrict__ iph,
                                                    float* __restrict__ out_final){
  __shared__ double sc[256];
  int tid = threadIdx.x;
  for (int b=0;b<B_;b++){
    sc[tid] = (tid < NCHUNK) ? g_chunksum[b*NCHUNK+tid] : 0.0;
    __syncthreads();
    for (int off=1; off<256; off<<=1){
      double u = (tid>=off) ? sc[tid-off] : 0.0;
      __syncthreads();
      sc[tid] += u;
      __syncthreads();
    }
    double init = (double)iph[b];
    if (tid < NCHUNK) g_chunkoff[b*NCHUNK+tid] = ((tid==0)?0.0:sc[tid-1]) + init;
    if (tid == 0){
      double tot = sc[NCHUNK-1] + init;
      out_final[b] = (float)fmod(tot, TWO_PI_D);
    }
    __syncthreads();
  }
}

__global__ __launch_bounds__(256) void k_phase(const float* __restrict__ f0, const float* __restrict__ vr,
                                               const float* __restrict__ vd){
  int b = blockIdx.x / NCHUNK, c = blockIdx.x % NCHUNK;
  int tid = threadIdx.x;
  int t = c*256 + tid;
  int idx = b*T_ + t;
  double f0v;
  double v = dphase_at(f0, vr, vd, idx, t, &f0v);
  int lane = tid & 63, wid = tid >> 6;
  for (int o=1;o<64;o<<=1){ double u = __shfl_up(v, o); if (lane >= o) v += u; }
  __shared__ double wsum[4];
  if (lane == 63) wsum[wid] = v;
  __syncthreads();
  double woff = 0.0;
  #pragma unroll
  for (int w=0; w<4; w++) if (w < wid) woff += wsum[w];
  double fund = g_chunkoff[b*NCHUNK+c] + woff + v;
  g_fmod[idx] = (float)fmod(fund, TWO_PI_D);
  g_f0vd[idx] = f0v;
}

// ---------------- harmonic additive synth ----------------
#define TT_ 64
__global__ __launch_bounds__(256) void k_signal(const float* __restrict__ amps,
                                                const float* __restrict__ goq){
  __shared__ __align__(16) float As[TT_*100];
  int b = blockIdx.x / (T_/TT_), c = blockIdx.x % (T_/TT_);
  int t0 = c*TT_;
  const float4* ag = (const float4*)(amps + ((size_t)b*T_ + t0)*H_);
  for (int i4 = threadIdx.x; i4 < TT_*H_/4; i4 += 256){
    int row = i4 / 24, col4 = i4 - row*24;
    float4 v = ag[i4];
    *((float4*)&As[row*100 + col4*4]) = v;
  }
  __syncthreads();
  int tl = threadIdx.x >> 2, part = threadIdx.x & 3;
  int t = t0 + tl;
  int idx = b*T_ + t;
  float r = g_fmod[idx];
  double f0vd = g_f0vd[idx];
  float oq = goq[idx];
  float k1 = 1.57079632679f / oq;
  float k2 = 1.57079632679f / (1.0f - oq);
  float sum = 0.f;
  const float4* Ar = (const float4*)&As[tl*100 + part*24];
  #pragma unroll
  for (int j4=0;j4<6;j4++){
    float4 a4 = Ar[j4];
    float av0[4] = {a4.x, a4.y, a4.z, a4.w};
    #pragma unroll
    for (int e=0;e<4;e++){
      int h = part*24 + j4*4 + e;
      float nn = (float)(h+1);
      float amp = ((double)(h+1) * f0vd < 22050.0) ? av0[e] : 0.0f;
      float fr = r * nn * 0.15915494309189535f;
      fr = fr - floorf(fr);
      float a1 = fr * k1;
      float a2 = (fr - oq) * k2;
      float s = __sinf(a1);
      float cc = __cosf(a2);
      float v = (fr < oq) ? s*s : cc*cc;
      sum = fmaf(v - 0.5f, amp, sum);
    }
  }
  sum += __shfl_xor(sum, 1);
  sum += __shfl_xor(sum, 2);
  if (part == 0) g_signal[idx] = sum;
}

// ---------------- FFT: N = 64000 = 512 * 125 ----------------
template<int SGN>
__device__ __forceinline__ float2* fft512_stages(float2* bufA, float2* bufB, int tid){
  float2* src = bufA; float2* dst = bufB;
  #pragma unroll
  for (int st=0; st<9; st++){
    const int s = 1<<st;
    const int n = 512>>st;
    const int m = n>>1;
    int p = tid >> st;
    int q = tid & (s-1);
    float2 a  = src[q + s*p];
    float2 bb = src[q + s*(p+m)];
    float ang = (float)SGN * ((float)(2.0*M_PI)/(float)n) * (float)p;
    float sw, cw; __sincosf(ang, &sw, &cw);
    dst[q + 2*s*p]     = cadd(a, bb);
    dst[q + 2*s*p + s] = cmul(make_float2(cw, sw), csub(a, bb));
    __syncthreads();
    float2* tp = src; src = dst; dst = tp;
  }
  return src;
}

__device__ __forceinline__ cplx w5k(int k, float sgn){
  const float C[5] = {1.f, 0.30901699f, -0.80901699f, -0.80901699f, 0.30901699f};
  const float S[5] = {0.f, 0.95105652f, 0.58778525f, -0.58778525f, -0.95105652f};
  return make_float2(C[k], sgn*S[k]);
}

template<int SGN>
__device__ __forceinline__ float2* fft125_rows(float2* bufA, float2* bufB, int tid){
  float2* src = bufA; float2* dst = bufB;
  #pragma unroll
  for (int st=0; st<3; st++){
    const int s = (st==0)?1:((st==1)?5:25);
    const int n = (st==0)?125:((st==1)?25:5);
    const int m = n/5;
    if (tid < 200){
      int row = tid/25, w = tid - row*25;
      int p = w/s, q = w - p*s;
      int base = row*125 + q;
      float2 a0 = src[base + s*p];
      float2 a1 = src[base + s*(p+m)];
      float2 a2 = src[base + s*(p+2*m)];
      float2 a3 = src[base + s*(p+3*m)];
      float2 a4 = src[base + s*(p+4*m)];
      #pragma unroll
      for (int r2=0;r2<5;r2++){
        float2 acc = a0;
        acc = cadd(acc, cmul(a1, w5k((1*r2)%5, (float)SGN)));
        acc = cadd(acc, cmul(a2, w5k((2*r2)%5, (float)SGN)));
        acc = cadd(acc, cmul(a3, w5k((3*r2)%5, (float)SGN)));
        acc = cadd(acc, cmul(a4, w5k((4*r2)%5, (float)SGN)));
        float ang = (float)SGN * ((float)(2.0*M_PI)/(float)n) * (float)(p*r2);
        float sw,cw; __sincosf(ang,&sw,&cw);
        dst[base + s*(5*p+r2)] = cmul(make_float2(cw,sw), acc);
      }
    }
    __syncthreads();
    float2* tp = src; src = dst; dst = tp;
  }
  return src;
}

__global__ __launch_bounds__(256) void k_fft512_fwd(){
  int b = blockIdx.x / 125, n1 = blockIdx.x % 125;
  int tid = threadIdx.x;
  __shared__ float2 bufA[512];
  __shared__ float2 bufB[512];
  for (int i=tid;i<512;i+=256) bufA[i] = make_float2(g_signal[b*T_ + n1 + 125*i], 0.f);
  __syncthreads();
  float2* res = fft512_stages<-1>(bufA, bufB, tid);
  for (int i=tid;i<512;i+=256){
    float ang = -(float)(2.0*M_PI/64000.0) * (float)(n1*i);
    float sw,cw; __sincosf(ang,&sw,&cw);
    g_W1[((size_t)b*512 + i)*125 + n1] = cmul(make_float2(cw,sw), res[i]);
  }
}

__global__ __launch_bounds__(256) void k_fft125_mid(const float* __restrict__ ffq,
                                                    const float* __restrict__ fbw,
                                                    const float* __restrict__ fgn){
  int b = blockIdx.x / 64;
  int k2base = (blockIdx.x % 64) * 8;
  int tid = threadIdx.x;
  __shared__ float2 bufA[1000];
  __shared__ float2 bufB[1000];
  const float2* gin = g_W1 + ((size_t)b*512 + k2base)*125;
  for (int i=tid;i<1000;i+=256) bufA[i] = gin[i];
  float fcv[4], bwv[4], gv[4];
  #pragma unroll
  for (int j=0;j<4;j++){
    size_t base = ((size_t)b*T_ + T_/2)*4 + j;
    fcv[j] = ffq[base]; bwv[j] = fbw[base]; gv[j] = fgn[base];
  }
  __syncthreads();
  float2* res = fft125_rows<-1>(bufA, bufB, tid);
  for (int i=tid;i<1000;i+=256){
    int row = i/125, kk1 = i - row*125;
    int f = (k2base+row) + 512*kk1;
    int fi = (f <= 32000) ? f : (64000 - f);
    float freq = (float)fi * 0.6890625f;
    float resp = 0.f;
    #pragma unroll
    for (int j=0;j<4;j++){
      float dd = (freq - fcv[j]) / (bwv[j]*0.5f);
      resp += gv[j] / (1.0f + dd*dd);
    }
    res[i] = make_float2(res[i].x*resp, res[i].y*resp);
  }
  __syncthreads();
  float2* other = (res == bufA) ? bufB : bufA;
  float2* res2 = fft125_rows<1>(res, other, tid);
  for (int i=tid;i<1000;i+=256){
    int row = i/125, n1 = i - row*125;
    int k2 = k2base + row;
    float ang = (float)(2.0*M_PI/64000.0) * (float)(n1*k2);
    float sw,cw; __sincosf(ang,&sw,&cw);
    g_Z[((size_t)b*125 + n1)*512 + k2] = cmul(make_float2(cw,sw), res2[i]);
  }
}

__global__ __launch_bounds__(256) void k_fft512_inv(const float* __restrict__ brth,
                                                    float* __restrict__ outp){
  int b = blockIdx.x / 125, n1 = blockIdx.x % 125;
  int tid = threadIdx.x;
  __shared__ float2 bufA[512];
  __shared__ float2 bufB[512];
  const float2* gin = g_Z + ((size_t)b*125 + n1)*512;
  for (int i=tid;i<512;i+=256) bufA[i] = gin[i];
  __syncthreads();
  float2* res = fft512_stages<1>(bufA, bufB, tid);
  float mean = (float)g_stats[b*2], rstd = (float)g_stats[b*2+1];
  for (int i=tid;i<512;i+=256){
    int t = n1 + 125*i;
    int idx = b*T_ + t;
    float filt = res[i].x * (1.0f/64000.0f);
    float br = brth[idx];
    float breath = (g_shaped[idx] - mean) * rstd;
    outp[idx] = filt*(1.0f - br) + breath*br;
  }
}

// ---------------- breath noise: partitionable threefry, XOR of output lanes ----------------
__device__ __forceinline__ uint32_t rotl32(uint32_t x, int r){ return (x<<r)|(x>>(32-r)); }

// f32-faithful to XLA: u = max(lo, f*2.0f + lo) in f32; Giles erfinv f32; *sqrt(2)
__device__ __forceinline__ float bits_to_normal(uint32_t bits){
  uint32_t mbits = (bits >> 9) | 0x3F800000u;
  float f = __uint_as_float(mbits) - 1.0f;
  const float lo = -0.99999994f;
  float x = f * 2.0f + lo;
  x = fmaxf(lo, x);
  float w = -log1pf(-x*x);
  float p;
  if (w < 5.0f){
    w -= 2.5f;
    p = 2.81022636e-08f;
    p = fmaf(p, w, 3.43273939e-07f);
    p = fmaf(p, w, -3.5233877e-06f);
    p = fmaf(p, w, -4.39150654e-06f);
    p = fmaf(p, w, 0.00021858087f);
    p = fmaf(p, w, -0.00125372503f);
    p = fmaf(p, w, -0.00417768164f);
    p = fmaf(p, w, 0.246640727f);
    p = fmaf(p, w, 1.50140941f);
  } else {
    w = sqrtf(w) - 3.0f;
    p = -0.000200214257f;
    p = fmaf(p, w, 0.000100950558f);
    p = fmaf(p, w, 0.00134934322f);
    p = fmaf(p, w, -0.00367342844f);
    p = fmaf(p, w, 0.00573950773f);
    p = fmaf(p, w, -0.0076224613f);
    p = fmaf(p, w, 0.00943887047f);
    p = fmaf(p, w, 1.00167406f);
    p = fmaf(p, w, 2.83297682f);
  }
  return 1.4142135623730951f * (p * x);
}

__global__ __launch_bounds__(256) void k_noise(){
  uint32_t i = blockIdx.x*256u + threadIdx.x;   // one u64 counter (0, i) per element
  uint32_t x0 = 0u, x1 = i;
  const uint32_t ks0 = 0u, ks1 = 42u, ks2 = 0u ^ 42u ^ 0x1BD11BDAu;
  x0 += ks0; x1 += ks1;
  #define TFR(r) { x0 += x1; x1 = rotl32(x1, r); x1 ^= x0; }
  TFR(13) TFR(15) TFR(26) TFR(6)   x0 += ks1; x1 += ks2 + 1u;
  TFR(17) TFR(29) TFR(16) TFR(24)  x0 += ks2; x1 += ks0 + 2u;
  TFR(13) TFR(15) TFR(26) TFR(6)   x0 += ks0; x1 += ks1 + 3u;
  TFR(17) TFR(29) TFR(16) TFR(24)  x0 += ks1; x1 += ks2 + 4u;
  TFR(13) TFR(15) TFR(26) TFR(6)   x0 += ks2; x1 += ks0 + 5u;
  #undef TFR
  // partitionable 32-bit draw (u64-free backend form): out0 ^ out1
  g_noise[i] = bits_to_normal(x0 ^ x1);
}

__constant__ int KSZc[8] = {129,91,65,45,33,23,17,11};

__global__ void k_kern(const float* __restrict__ bss){
  int b = blockIdx.x;
  int tid = threadIdx.x;
  __shared__ float wn[8];
  if (tid < 8){
    int ksz = KSZc[tid];
    float sig = (float)ksz / 6.0f;
    float inv2s2 = 1.0f/(2.0f*sig*sig);
    int c = ksz>>1;
    float s = 0.f;
    for (int j=0;j<ksz;j++){ float d = (float)(j - c); s += expf(-d*d*inv2s2); }
    float w = bss[((size_t)b*T_ + T_/2)*8 + tid];
    wn[tid] = w / s;
  }
  __syncthreads();
  if (tid < 129){
    int tau = tid - 64;
    float acc = 0.f;
    #pragma unroll
    for (int i=0;i<8;i++){
      int ksz = KSZc[i]; int hw = ksz>>1;
      if (tau >= -hw && tau <= hw){
        float sig = (float)ksz/6.0f;
        float inv2s2 = 1.0f/(2.0f*sig*sig);
        acc += expf(-(float)(tau*tau)*inv2s2) * wn[i];
      }
    }
    g_Kcomb[b*132 + tid] = acc;
  }
}

__global__ __launch_bounds__(256) void k_conv(){
  int b = blockIdx.x / (T_/256), c = blockIdx.x % (T_/256);
  int t0 = c*256, tid = threadIdx.x;
  __shared__ float ns[384];
  __shared__ float kl[129];
  for (int i=tid;i<384;i+=256){ int t = t0 - 64 + i; ns[i] = (t>=0 && t<T_) ? g_noise[b*T_+t] : 0.f; }
  if (tid < 129) kl[tid] = g_Kcomb[b*132+tid];
  __syncthreads();
  float acc = 0.f;
  for (int j=0;j<129;j++) acc = fmaf(ns[tid+j], kl[j], acc);
  g_shaped[b*T_ + t0 + tid] = acc;
}

__global__ __launch_bounds__(256) void k_stats(){
  int b = blockIdx.x; int tid = threadIdx.x;
  double s1=0.0, s2=0.0;
  for (int t=tid; t<T_; t+=256){ double x = (double)g_shaped[b*T_+t]; s1 += x; s2 += x*x; }
  for (int o=1;o<64;o<<=1){ s1 += __shfl_down(s1,o); s2 += __shfl_down(s2,o); }
  __shared__ double a1[4], a2[4];
  int lane = tid&63, wid = tid>>6;
  if (lane==0){ a1[wid]=s1; a2[wid]=s2; }
  __syncthreads();
  if (tid==0){
    double S1=a1[0]+a1[1]+a1[2]+a1[3], S2=a2[0]+a2[1]+a2[2]+a2[3];
    double mean = S1 / (double)T_;
    double var = (S2 - (double)T_*mean*mean) / (double)(T_-1);
    if (var < 0.0) var = 0.0;
    double rstd = 1.0/(sqrt(var) + 1e-8);
    g_stats[b*2] = mean; g_stats[b*2+1] = rstd;
  }
}

extern "C" void kernel_launch(void* const* d_in, const int* in_sizes, int n_in,
                              void* d_out, int out_size, void* d_ws, size_t ws_size,
                              hipStream_t stream){
  (void)in_sizes; (void)n_in; (void)out_size; (void)d_ws; (void)ws_size;
  const float* f0   = (const float*)d_in[0];
  const float* amps = (const float*)d_in[1];
  const float* vr   = (const float*)d_in[2];
  const float* vd   = (const float*)d_in[3];
  const float* ffq  = (const float*)d_in[4];
  const float* fbw  = (const float*)d_in[5];
  const float* fgn  = (const float*)d_in[6];
  const float* goq  = (const float*)d_in[7];
  const float* brth = (const float*)d_in[9];
  const float* bss  = (const float*)d_in[10];
  const float* iph  = (const float*)d_in[11];
  float* out = (float*)d_out;

  // breath path
  k_noise<<<1000,256,0,stream>>>();
  k_kern<<<4,192,0,stream>>>(bss);
  k_conv<<<1000,256,0,stream>>>();
  k_stats<<<4,256,0,stream>>>();
  // phase path
  k_chunksum<<<1000,256,0,stream>>>(f0, vr, vd);
  k_scanchunks<<<1,256,0,stream>>>(iph, out + (size_t)B_*T_);
  k_phase<<<1000,256,0,stream>>>(f0, vr, vd);
  // harmonic synth
  k_signal<<<4000,256,0,stream>>>(amps, goq);
  // formant filter via four-step FFT + epilogue mix
  k_fft512_fwd<<<500,256,0,stream>>>();
  k_fft125_mid<<<256,256,0,stream>>>(ffq, fbw, fgn);
  k_fft512_inv<<<500,256,0,stream>>>(brth, out);
}

// Round 7
// 97.631 us; speedup vs baseline: 1.6334x; 1.6334x over previous
//
#include <hip/hip_runtime.h>
#include <math.h>
#include <stdint.h>

#define B_ 4
#define T_ 64000
#define H_ 96
#define NCHUNK 250
#define SBLK 64
#define TWO_PI_D 6.283185307179586

typedef float2 cplx;
__device__ __forceinline__ cplx cadd(cplx a, cplx b){ return make_float2(a.x+b.x, a.y+b.y); }
__device__ __forceinline__ cplx csub(cplx a, cplx b){ return make_float2(a.x-b.x, a.y-b.y); }
__device__ __forceinline__ cplx cmul(cplx a, cplx b){ return make_float2(a.x*b.x - a.y*b.y, a.x*b.y + a.y*b.x); }

// ---------------- static scratch ----------------
__device__ double g_f0vd[B_*T_];
__device__ double g_dp[B_*T_];
__device__ float  g_fmod[B_*T_];
__device__ float  g_signal[B_*T_];
__device__ float  g_noise[B_*T_];
__device__ float  g_shaped[B_*T_];
__device__ float2 g_W1[B_*512*125];
__device__ float2 g_Z[B_*125*512];
__device__ double g_chunksum[B_*NCHUNK];
__device__ double g_chunkoff[B_*NCHUNK];
__device__ float  g_Kcomb[B_*132];
__device__ double g_stats[B_*2];
__device__ double g_part[B_*SBLK*2];

// ---------------- phase increment in f64 ----------------
__device__ __forceinline__ double dphase_at(const float* __restrict__ f0,
                                            const float* __restrict__ vr,
                                            const float* __restrict__ vd,
                                            int idx, int t, double* f0v_out){
  double tt = (double)t / 44100.0;
  double sv = sin(TWO_PI_D * (double)vr[idx] * tt);
  double vf = exp2((double)vd[idx] / 12.0);
  double lm = log(vf);
  double vm = exp(sv * lm);
  double f0s = (double)f0[idx];
  double f0v = (f0s > 0.0) ? f0s * vm : f0s;
  *f0v_out = f0v;
  return TWO_PI_D * f0v / 44100.0;
}

__global__ __launch_bounds__(256) void k_chunksum(const float* __restrict__ f0, const float* __restrict__ vr,
                                                  const float* __restrict__ vd){
  int b = blockIdx.x / NCHUNK, c = blockIdx.x % NCHUNK;
  int tid = threadIdx.x;
  int t = c*256 + tid;
  int idx = b*T_ + t;
  double f0v;
  double v = dphase_at(f0, vr, vd, idx, t, &f0v);
  g_dp[idx] = v;
  g_f0vd[idx] = f0v;
  for (int o=1;o<64;o<<=1) v += __shfl_down(v, o);
  __shared__ double wsum[4];
  int lane = tid & 63, wid = tid >> 6;
  if (lane == 0) wsum[wid] = v;
  __syncthreads();
  if (tid == 0) g_chunksum[b*NCHUNK + c] = wsum[0]+wsum[1]+wsum[2]+wsum[3];
}

__global__ __launch_bounds__(256) void k_scanchunks(const float* __restrict__ iph,
                                                    float* __restrict__ out_final){
  __shared__ double sc[256];
  int tid = threadIdx.x;
  for (int b=0;b<B_;b++){
    sc[tid] = (tid < NCHUNK) ? g_chunksum[b*NCHUNK+tid] : 0.0;
    __syncthreads();
    for (int off=1; off<256; off<<=1){
      double u = (tid>=off) ? sc[tid-off] : 0.0;
      __syncthreads();
      sc[tid] += u;
      __syncthreads();
    }
    double init = (double)iph[b];
    if (tid < NCHUNK) g_chunkoff[b*NCHUNK+tid] = ((tid==0)?0.0:sc[tid-1]) + init;
    if (tid == 0){
      double tot = sc[NCHUNK-1] + init;
      out_final[b] = (float)fmod(tot, TWO_PI_D);
    }
    __syncthreads();
  }
}

__global__ __launch_bounds__(256) void k_phase(){
  int b = blockIdx.x / NCHUNK, c = blockIdx.x % NCHUNK;
  int tid = threadIdx.x;
  int t = c*256 + tid;
  int idx = b*T_ + t;
  double v = g_dp[idx];
  int lane = tid & 63, wid = tid >> 6;
  for (int o=1;o<64;o<<=1){ double u = __shfl_up(v, o); if (lane >= o) v += u; }
  __shared__ double wsum[4];
  if (lane == 63) wsum[wid] = v;
  __syncthreads();
  double woff = 0.0;
  #pragma unroll
  for (int w=0; w<4; w++) if (w < wid) woff += wsum[w];
  double fund = g_chunkoff[b*NCHUNK+c] + woff + v;
  g_fmod[idx] = (float)fmod(fund, TWO_PI_D);
}

// ---------------- harmonic additive synth ----------------
#define TT_ 64
__global__ __launch_bounds__(256) void k_signal(const float* __restrict__ amps,
                                                const float* __restrict__ goq){
  __shared__ __align__(16) float As[TT_*100];
  int b = blockIdx.x / (T_/TT_), c = blockIdx.x % (T_/TT_);
  int t0 = c*TT_;
  const float4* ag = (const float4*)(amps + ((size_t)b*T_ + t0)*H_);
  for (int i4 = threadIdx.x; i4 < TT_*H_/4; i4 += 256){
    int row = i4 / 24, col4 = i4 - row*24;
    float4 v = ag[i4];
    *((float4*)&As[row*100 + col4*4]) = v;
  }
  __syncthreads();
  int tl = threadIdx.x >> 2, part = threadIdx.x & 3;
  int t = t0 + tl;
  int idx = b*T_ + t;
  float r = g_fmod[idx];
  double f0vd = g_f0vd[idx];
  float oq = goq[idx];
  float k1 = 1.57079632679f / oq;
  float k2 = 1.57079632679f / (1.0f - oq);
  float sum = 0.f;
  const float4* Ar = (const float4*)&As[tl*100 + part*24];
  #pragma unroll
  for (int j4=0;j4<6;j4++){
    float4 a4 = Ar[j4];
    float av0[4] = {a4.x, a4.y, a4.z, a4.w};
    #pragma unroll
    for (int e=0;e<4;e++){
      int h = part*24 + j4*4 + e;
      float nn = (float)(h+1);
      float amp = ((double)(h+1) * f0vd < 22050.0) ? av0[e] : 0.0f;
      float fr = r * nn * 0.15915494309189535f;
      fr = fr - floorf(fr);
      float a1 = fr * k1;
      float a2 = (fr - oq) * k2;
      float s = __sinf(a1);
      float cc = __cosf(a2);
      float v = (fr < oq) ? s*s : cc*cc;
      sum = fmaf(v - 0.5f, amp, sum);
    }
  }
  sum += __shfl_xor(sum, 1);
  sum += __shfl_xor(sum, 2);
  if (part == 0) g_signal[idx] = sum;
}

// ---------------- FFT: N = 64000 = 512 * 125 ----------------
template<int SGN>
__device__ __forceinline__ float2* fft512_stages(float2* bufA, float2* bufB, int tid){
  float2* src = bufA; float2* dst = bufB;
  #pragma unroll
  for (int st=0; st<9; st++){
    const int s = 1<<st;
    const int n = 512>>st;
    const int m = n>>1;
    int p = tid >> st;
    int q = tid & (s-1);
    float2 a  = src[q + s*p];
    float2 bb = src[q + s*(p+m)];
    float ang = (float)SGN * ((float)(2.0*M_PI)/(float)n) * (float)p;
    float sw, cw; __sincosf(ang, &sw, &cw);
    dst[q + 2*s*p]     = cadd(a, bb);
    dst[q + 2*s*p + s] = cmul(make_float2(cw, sw), csub(a, bb));
    __syncthreads();
    float2* tp = src; src = dst; dst = tp;
  }
  return src;
}

__device__ __forceinline__ cplx w5k(int k, float sgn){
  const float C[5] = {1.f, 0.30901699f, -0.80901699f, -0.80901699f, 0.30901699f};
  const float S[5] = {0.f, 0.95105652f, 0.58778525f, -0.58778525f, -0.95105652f};
  return make_float2(C[k], sgn*S[k]);
}

template<int SGN>
__device__ __forceinline__ float2* fft125_rows(float2* bufA, float2* bufB, int tid){
  float2* src = bufA; float2* dst = bufB;
  #pragma unroll
  for (int st=0; st<3; st++){
    const int s = (st==0)?1:((st==1)?5:25);
    const int n = (st==0)?125:((st==1)?25:5);
    const int m = n/5;
    if (tid < 200){
      int row = tid/25, w = tid - row*25;
      int p = w/s, q = w - p*s;
      int base = row*125 + q;
      float2 a0 = src[base + s*p];
      float2 a1 = src[base + s*(p+m)];
      float2 a2 = src[base + s*(p+2*m)];
      float2 a3 = src[base + s*(p+3*m)];
      float2 a4 = src[base + s*(p+4*m)];
      #pragma unroll
      for (int r2=0;r2<5;r2++){
        float2 acc = a0;
        acc = cadd(acc, cmul(a1, w5k((1*r2)%5, (float)SGN)));
        acc = cadd(acc, cmul(a2, w5k((2*r2)%5, (float)SGN)));
        acc = cadd(acc, cmul(a3, w5k((3*r2)%5, (float)SGN)));
        acc = cadd(acc, cmul(a4, w5k((4*r2)%5, (float)SGN)));
        float ang = (float)SGN * ((float)(2.0*M_PI)/(float)n) * (float)(p*r2);
        float sw,cw; __sincosf(ang,&sw,&cw);
        dst[base + s*(5*p+r2)] = cmul(make_float2(cw,sw), acc);
      }
    }
    __syncthreads();
    float2* tp = src; src = dst; dst = tp;
  }
  return src;
}

__global__ __launch_bounds__(256) void k_fft512_fwd(){
  int b = blockIdx.x / 125, n1 = blockIdx.x % 125;
  int tid = threadIdx.x;
  __shared__ float2 bufA[512];
  __shared__ float2 bufB[512];
  for (int i=tid;i<512;i+=256) bufA[i] = make_float2(g_signal[b*T_ + n1 + 125*i], 0.f);
  __syncthreads();
  float2* res = fft512_stages<-1>(bufA, bufB, tid);
  for (int i=tid;i<512;i+=256){
    float ang = -(float)(2.0*M_PI/64000.0) * (float)(n1*i);
    float sw,cw; __sincosf(ang,&sw,&cw);
    g_W1[((size_t)b*512 + i)*125 + n1] = cmul(make_float2(cw,sw), res[i]);
  }
}

__global__ __launch_bounds__(256) void k_fft125_mid(const float* __restrict__ ffq,
                                                    const float* __restrict__ fbw,
                                                    const float* __restrict__ fgn){
  int b = blockIdx.x / 64;
  int k2base = (blockIdx.x % 64) * 8;
  int tid = threadIdx.x;
  __shared__ float2 bufA[1000];
  __shared__ float2 bufB[1000];
  const float2* gin = g_W1 + ((size_t)b*512 + k2base)*125;
  for (int i=tid;i<1000;i+=256) bufA[i] = gin[i];
  float fcv[4], bwv[4], gv[4];
  #pragma unroll
  for (int j=0;j<4;j++){
    size_t base = ((size_t)b*T_ + T_/2)*4 + j;
    fcv[j] = ffq[base]; bwv[j] = fbw[base]; gv[j] = fgn[base];
  }
  __syncthreads();
  float2* res = fft125_rows<-1>(bufA, bufB, tid);
  for (int i=tid;i<1000;i+=256){
    int row = i/125, kk1 = i - row*125;
    int f = (k2base+row) + 512*kk1;
    int fi = (f <= 32000) ? f : (64000 - f);
    float freq = (float)fi * 0.6890625f;
    float resp = 0.f;
    #pragma unroll
    for (int j=0;j<4;j++){
      float dd = (freq - fcv[j]) / (bwv[j]*0.5f);
      resp += gv[j] / (1.0f + dd*dd);
    }
    res[i] = make_float2(res[i].x*resp, res[i].y*resp);
  }
  __syncthreads();
  float2* other = (res == bufA) ? bufB : bufA;
  float2* res2 = fft125_rows<1>(res, other, tid);
  for (int i=tid;i<1000;i+=256){
    int row = i/125, n1 = i - row*125;
    int k2 = k2base + row;
    float ang = (float)(2.0*M_PI/64000.0) * (float)(n1*k2);
    float sw,cw; __sincosf(ang,&sw,&cw);
    g_Z[((size_t)b*125 + n1)*512 + k2] = cmul(make_float2(cw,sw), res2[i]);
  }
}

__global__ __launch_bounds__(256) void k_fft512_inv(const float* __restrict__ brth,
                                                    float* __restrict__ outp){
  int b = blockIdx.x / 125, n1 = blockIdx.x % 125;
  int tid = threadIdx.x;
  __shared__ float2 bufA[512];
  __shared__ float2 bufB[512];
  const float2* gin = g_Z + ((size_t)b*125 + n1)*512;
  for (int i=tid;i<512;i+=256) bufA[i] = gin[i];
  __syncthreads();
  float2* res = fft512_stages<1>(bufA, bufB, tid);
  float mean = (float)g_stats[b*2], rstd = (float)g_stats[b*2+1];
  for (int i=tid;i<512;i+=256){
    int t = n1 + 125*i;
    int idx = b*T_ + t;
    float filt = res[i].x * (1.0f/64000.0f);
    float br = brth[idx];
    float breath = (g_shaped[idx] - mean) * rstd;
    outp[idx] = filt*(1.0f - br) + breath*br;
  }
}

// ---------------- breath noise: partitionable threefry, out0^out1 ----------------
__device__ __forceinline__ uint32_t rotl32(uint32_t x, int r){ return (x<<r)|(x>>(32-r)); }

__device__ __forceinline__ float bits_to_normal(uint32_t bits){
  uint32_t mbits = (bits >> 9) | 0x3F800000u;
  float f = __uint_as_float(mbits) - 1.0f;
  const float lo = -0.99999994f;
  float x = f * 2.0f + lo;
  x = fmaxf(lo, x);
  float w = -log1pf(-x*x);
  float p;
  if (w < 5.0f){
    w -= 2.5f;
    p = 2.81022636e-08f;
    p = fmaf(p, w, 3.43273939e-07f);
    p = fmaf(p, w, -3.5233877e-06f);
    p = fmaf(p, w, -4.39150654e-06f);
    p = fmaf(p, w, 0.00021858087f);
    p = fmaf(p, w, -0.00125372503f);
    p = fmaf(p, w, -0.00417768164f);
    p = fmaf(p, w, 0.246640727f);
    p = fmaf(p, w, 1.50140941f);
  } else {
    w = sqrtf(w) - 3.0f;
    p = -0.000200214257f;
    p = fmaf(p, w, 0.000100950558f);
    p = fmaf(p, w, 0.00134934322f);
    p = fmaf(p, w, -0.00367342844f);
    p = fmaf(p, w, 0.00573950773f);
    p = fmaf(p, w, -0.0076224613f);
    p = fmaf(p, w, 0.00943887047f);
    p = fmaf(p, w, 1.00167406f);
    p = fmaf(p, w, 2.83297682f);
  }
  return 1.4142135623730951f * (p * x);
}

__global__ __launch_bounds__(256) void k_noise(){
  uint32_t i = blockIdx.x*256u + threadIdx.x;
  uint32_t x0 = 0u, x1 = i;
  const uint32_t ks0 = 0u, ks1 = 42u, ks2 = 0u ^ 42u ^ 0x1BD11BDAu;
  x0 += ks0; x1 += ks1;
  #define TFR(r) { x0 += x1; x1 = rotl32(x1, r); x1 ^= x0; }
  TFR(13) TFR(15) TFR(26) TFR(6)   x0 += ks1; x1 += ks2 + 1u;
  TFR(17) TFR(29) TFR(16) TFR(24)  x0 += ks2; x1 += ks0 + 2u;
  TFR(13) TFR(15) TFR(26) TFR(6)   x0 += ks0; x1 += ks1 + 3u;
  TFR(17) TFR(29) TFR(16) TFR(24)  x0 += ks1; x1 += ks2 + 4u;
  TFR(13) TFR(15) TFR(26) TFR(6)   x0 += ks2; x1 += ks0 + 5u;
  #undef TFR
  g_noise[i] = bits_to_normal(x0 ^ x1);
}

__constant__ int KSZc[8] = {129,91,65,45,33,23,17,11};

__global__ void k_kern(const float* __restrict__ bss){
  int b = blockIdx.x;
  int tid = threadIdx.x;
  __shared__ float wn[8];
  if (tid < 8){
    int ksz = KSZc[tid];
    float sig = (float)ksz / 6.0f;
    float inv2s2 = 1.0f/(2.0f*sig*sig);
    int c = ksz>>1;
    float s = 0.f;
    for (int j=0;j<ksz;j++){ float d = (float)(j - c); s += expf(-d*d*inv2s2); }
    float w = bss[((size_t)b*T_ + T_/2)*8 + tid];
    wn[tid] = w / s;
  }
  __syncthreads();
  if (tid < 129){
    int tau = tid - 64;
    float acc = 0.f;
    #pragma unroll
    for (int i=0;i<8;i++){
      int ksz = KSZc[i]; int hw = ksz>>1;
      if (tau >= -hw && tau <= hw){
        float sig = (float)ksz/6.0f;
        float inv2s2 = 1.0f/(2.0f*sig*sig);
        acc += expf(-(float)(tau*tau)*inv2s2) * wn[i];
      }
    }
    g_Kcomb[b*132 + tid] = acc;
  }
}

__global__ __launch_bounds__(256) void k_conv(){
  int b = blockIdx.x / (T_/256), c = blockIdx.x % (T_/256);
  int t0 = c*256, tid = threadIdx.x;
  __shared__ float ns[384];
  __shared__ float kl[129];
  for (int i=tid;i<384;i+=256){ int t = t0 - 64 + i; ns[i] = (t>=0 && t<T_) ? g_noise[b*T_+t] : 0.f; }
  if (tid < 129) kl[tid] = g_Kcomb[b*132+tid];
  __syncthreads();
  float acc = 0.f;
  for (int j=0;j<129;j++) acc = fmaf(ns[tid+j], kl[j], acc);
  g_shaped[b*T_ + t0 + tid] = acc;
}

// ---------------- stats: two-stage tree reduction ----------------
__global__ __launch_bounds__(256) void k_stats1(){
  int b = blockIdx.x / SBLK, blk = blockIdx.x % SBLK;
  int tid = threadIdx.x;
  const int CH = T_ / SBLK;           // 1000
  int base = b*T_ + blk*CH;
  double s1=0.0, s2=0.0;
  for (int j = tid; j < CH; j += 256){
    double x = (double)g_shaped[base + j];
    s1 += x; s2 += x*x;
  }
  for (int o=1;o<64;o<<=1){ s1 += __shfl_down(s1,o); s2 += __shfl_down(s2,o); }
  __shared__ double a1[4], a2[4];
  int lane = tid&63, wid = tid>>6;
  if (lane==0){ a1[wid]=s1; a2[wid]=s2; }
  __syncthreads();
  if (tid==0){
    g_part[(b*SBLK+blk)*2]   = a1[0]+a1[1]+a1[2]+a1[3];
    g_part[(b*SBLK+blk)*2+1] = a2[0]+a2[1]+a2[2]+a2[3];
  }
}

__global__ void k_stats2(){
  int b = blockIdx.x;
  int lane = threadIdx.x;           // 64 threads
  double s1 = g_part[(b*SBLK+lane)*2];
  double s2 = g_part[(b*SBLK+lane)*2+1];
  for (int o=1;o<64;o<<=1){ s1 += __shfl_down(s1,o); s2 += __shfl_down(s2,o); }
  if (lane==0){
    double mean = s1 / (double)T_;
    double var = (s2 - (double)T_*mean*mean) / (double)(T_-1);
    if (var < 0.0) var = 0.0;
    double rstd = 1.0/(sqrt(var) + 1e-8);
    g_stats[b*2] = mean; g_stats[b*2+1] = rstd;
  }
}

extern "C" void kernel_launch(void* const* d_in, const int* in_sizes, int n_in,
                              void* d_out, int out_size, void* d_ws, size_t ws_size,
                              hipStream_t stream){
  (void)in_sizes; (void)n_in; (void)out_size; (void)d_ws; (void)ws_size;
  const float* f0   = (const float*)d_in[0];
  const float* amps = (const float*)d_in[1];
  const float* vr   = (const float*)d_in[2];
  const float* vd   = (const float*)d_in[3];
  const float* ffq  = (const float*)d_in[4];
  const float* fbw  = (const float*)d_in[5];
  const float* fgn  = (const float*)d_in[6];
  const float* goq  = (const float*)d_in[7];
  const float* brth = (const float*)d_in[9];
  const float* bss  = (const float*)d_in[10];
  const float* iph  = (const float*)d_in[11];
  float* out = (float*)d_out;

  // breath path
  k_noise<<<1000,256,0,stream>>>();
  k_kern<<<4,192,0,stream>>>(bss);
  k_conv<<<1000,256,0,stream>>>();
  k_stats1<<<B_*SBLK,256,0,stream>>>();
  k_stats2<<<B_,64,0,stream>>>();
  // phase path
  k_chunksum<<<1000,256,0,stream>>>(f0, vr, vd);
  k_scanchunks<<<1,256,0,stream>>>(iph, out + (size_t)B_*T_);
  k_phase<<<1000,256,0,stream>>>();
  // harmonic synth
  k_signal<<<4000,256,0,stream>>>(amps, goq);
  // formant filter via four-step FFT + epilogue mix
  k_fft512_fwd<<<500,256,0,stream>>>();
  k_fft125_mid<<<256,256,0,stream>>>(ffq, fbw, fgn);
  k_fft512_inv<<<500,256,0,stream>>>(brth, out);
}

// Round 8
// 84.016 us; speedup vs baseline: 1.8981x; 1.1621x over previous
//
#include <hip/hip_runtime.h>
#include <math.h>
#include <stdint.h>

#define B_ 4
#define T_ 64000
#define H_ 96
#define NCH 1000          // 64-sample chunks per batch
#define TT_ 64
#define TWO_PI_D 6.283185307179586

typedef float2 cplx;
__device__ __forceinline__ cplx cadd(cplx a, cplx b){ return make_float2(a.x+b.x, a.y+b.y); }
__device__ __forceinline__ cplx csub(cplx a, cplx b){ return make_float2(a.x-b.x, a.y-b.y); }
__device__ __forceinline__ cplx cmul(cplx a, cplx b){ return make_float2(a.x*b.x - a.y*b.y, a.x*b.y + a.y*b.x); }

// ---------------- static scratch ----------------
__device__ double g_dp[B_*T_];
__device__ unsigned char g_hcnt[B_*T_];
__device__ float  g_signal[B_*T_];
__device__ float  g_shaped[B_*T_];
__device__ float2 g_W1[B_*512*125];
__device__ float2 g_Z[B_*125*512];
__device__ double g_chunksum[B_*NCH];
__device__ double g_chunkoff[B_*NCH];
__device__ double g_stats[B_*2];
__device__ double g_part[B_*250*2];

// ---------------- threefry (partitionable, out0^out1) ----------------
__device__ __forceinline__ uint32_t rotl32(uint32_t x, int r){ return (x<<r)|(x>>(32-r)); }

__device__ __forceinline__ uint32_t threefry_bits(uint32_t i){
  uint32_t x0 = 0u, x1 = i;
  const uint32_t ks0 = 0u, ks1 = 42u, ks2 = 0u ^ 42u ^ 0x1BD11BDAu;
  x0 += ks0; x1 += ks1;
  #define TFR(r) { x0 += x1; x1 = rotl32(x1, r); x1 ^= x0; }
  TFR(13) TFR(15) TFR(26) TFR(6)   x0 += ks1; x1 += ks2 + 1u;
  TFR(17) TFR(29) TFR(16) TFR(24)  x0 += ks2; x1 += ks0 + 2u;
  TFR(13) TFR(15) TFR(26) TFR(6)   x0 += ks0; x1 += ks1 + 3u;
  TFR(17) TFR(29) TFR(16) TFR(24)  x0 += ks1; x1 += ks2 + 4u;
  TFR(13) TFR(15) TFR(26) TFR(6)   x0 += ks2; x1 += ks0 + 5u;
  #undef TFR
  return x0 ^ x1;
}

__device__ __forceinline__ float bits_to_normal(uint32_t bits){
  uint32_t mbits = (bits >> 9) | 0x3F800000u;
  float f = __uint_as_float(mbits) - 1.0f;
  const float lo = -0.99999994f;
  float x = f * 2.0f + lo;
  x = fmaxf(lo, x);
  float w = -log1pf(-x*x);
  float p;
  if (w < 5.0f){
    w -= 2.5f;
    p = 2.81022636e-08f;
    p = fmaf(p, w, 3.43273939e-07f);
    p = fmaf(p, w, -3.5233877e-06f);
    p = fmaf(p, w, -4.39150654e-06f);
    p = fmaf(p, w, 0.00021858087f);
    p = fmaf(p, w, -0.00125372503f);
    p = fmaf(p, w, -0.00417768164f);
    p = fmaf(p, w, 0.246640727f);
    p = fmaf(p, w, 1.50140941f);
  } else {
    w = sqrtf(w) - 3.0f;
    p = -0.000200214257f;
    p = fmaf(p, w, 0.000100950558f);
    p = fmaf(p, w, 0.00134934322f);
    p = fmaf(p, w, -0.00367342844f);
    p = fmaf(p, w, 0.00573950773f);
    p = fmaf(p, w, -0.0076224613f);
    p = fmaf(p, w, 0.00943887047f);
    p = fmaf(p, w, 1.00167406f);
    p = fmaf(p, w, 2.83297682f);
  }
  return 1.4142135623730951f * (p * x);
}

__constant__ int KSZc[8] = {129,91,65,45,33,23,17,11};

// ---------------- breath: noise + kernel + conv + stats partial ----------------
__global__ __launch_bounds__(256) void k_breath(const float* __restrict__ bss){
  int b = blockIdx.x / 250, c = blockIdx.x % 250;
  int t0 = c*256, tid = threadIdx.x;
  __shared__ float ns[384];
  __shared__ float kl[129];
  __shared__ float wn[8];
  if (tid < 8){
    int ksz = KSZc[tid];
    float sig = (float)ksz / 6.0f;
    float inv2s2 = 1.0f/(2.0f*sig*sig);
    int ctr = ksz>>1;
    float s = 0.f;
    for (int j=0;j<ksz;j++){ float d = (float)(j - ctr); s += expf(-d*d*inv2s2); }
    wn[tid] = bss[((size_t)b*T_ + T_/2)*8 + tid] / s;
  }
  for (int j = tid; j < 384; j += 256){
    int t = t0 - 64 + j;
    float v = 0.f;
    if (t >= 0 && t < T_) v = bits_to_normal(threefry_bits((uint32_t)(b*T_ + t)));
    ns[j] = v;
  }
  __syncthreads();
  if (tid < 129){
    int tau = tid - 64;
    float acc = 0.f;
    #pragma unroll
    for (int i=0;i<8;i++){
      int ksz = KSZc[i]; int hw = ksz>>1;
      if (tau >= -hw && tau <= hw){
        float sig = (float)ksz/6.0f;
        float inv2s2 = 1.0f/(2.0f*sig*sig);
        acc += expf(-(float)(tau*tau)*inv2s2) * wn[i];
      }
    }
    kl[tid] = acc;
  }
  __syncthreads();
  float acc = 0.f;
  for (int j=0;j<129;j++) acc = fmaf(ns[tid+j], kl[j], acc);
  g_shaped[b*T_ + t0 + tid] = acc;
  // stats partial
  double x = (double)acc;
  double s1 = x, s2 = x*x;
  for (int o=1;o<64;o<<=1){ s1 += __shfl_down(s1,o); s2 += __shfl_down(s2,o); }
  __shared__ double a1[4], a2[4];
  int lane = tid&63, wid = tid>>6;
  if (lane==0){ a1[wid]=s1; a2[wid]=s2; }
  __syncthreads();
  if (tid==0){
    g_part[(b*250+c)*2]   = a1[0]+a1[1]+a1[2]+a1[3];
    g_part[(b*250+c)*2+1] = a2[0]+a2[1]+a2[2]+a2[3];
  }
}

// ---------------- phase increments + harmonic counts + 64-chunk sums ----------------
__global__ __launch_bounds__(256) void k_chunksum(const float* __restrict__ f0, const float* __restrict__ vr,
                                                  const float* __restrict__ vd){
  int b = blockIdx.x / 250, c = blockIdx.x % 250;
  int tid = threadIdx.x;
  int t = c*256 + tid;
  int idx = b*T_ + t;
  double tt = (double)t / 44100.0;
  double sv = sin(TWO_PI_D * (double)vr[idx] * tt);
  double lm = (double)vd[idx] * 0.057762265046662105;   // ln2/12
  double vm = exp(sv * lm);
  double f0s = (double)f0[idx];
  double f0v = (f0s > 0.0) ? f0s * vm : f0s;
  int cnt = 0;
  #pragma unroll
  for (int n=1;n<=96;n++) cnt += ((double)n * f0v < 22050.0) ? 1 : 0;
  g_hcnt[idx] = (unsigned char)cnt;
  double v = TWO_PI_D * f0v / 44100.0;
  g_dp[idx] = v;
  int lane = tid & 63, wid = tid >> 6;
  for (int o=1;o<64;o<<=1) v += __shfl_down(v, o);
  if (lane == 0) g_chunksum[b*NCH + c*4 + wid] = v;   // chunk = t/64
}

// ---------------- scan 1000 chunks/batch + final phase + stats finish ----------------
__global__ __launch_bounds__(256) void k_scanstats(const float* __restrict__ iph,
                                                   float* __restrict__ out_final){
  int b = blockIdx.x;
  int tid = threadIdx.x;
  __shared__ double sc[256];
  double v0[4];
  double s = 0.0;
  #pragma unroll
  for (int k=0;k<4;k++){
    int ch = tid*4 + k;
    double x = (ch < NCH) ? g_chunksum[b*NCH+ch] : 0.0;
    v0[k] = x; s += x;
  }
  sc[tid] = s;
  __syncthreads();
  for (int off=1; off<256; off<<=1){
    double u = (tid>=off) ? sc[tid-off] : 0.0;
    __syncthreads();
    sc[tid] += u;
    __syncthreads();
  }
  double init = (double)iph[b];
  double excl = ((tid==0) ? 0.0 : sc[tid-1]) + init;
  #pragma unroll
  for (int k=0;k<4;k++){
    int ch = tid*4 + k;
    if (ch < NCH) g_chunkoff[b*NCH+ch] = excl;
    excl += v0[k];
  }
  if (tid == 255) out_final[b] = (float)fmod(sc[255] + init, TWO_PI_D);
  // stats finish (250 partials)
  double s1=0.0, s2=0.0;
  if (tid < 250){ s1 = g_part[(b*250+tid)*2]; s2 = g_part[(b*250+tid)*2+1]; }
  for (int o=1;o<64;o<<=1){ s1 += __shfl_down(s1,o); s2 += __shfl_down(s2,o); }
  __shared__ double a1[4], a2[4];
  int lane = tid&63, wid = tid>>6;
  if (lane==0){ a1[wid]=s1; a2[wid]=s2; }
  __syncthreads();
  if (tid==0){
    double S1=a1[0]+a1[1]+a1[2]+a1[3], S2=a2[0]+a2[1]+a2[2]+a2[3];
    double mean = S1 / (double)T_;
    double var = (S2 - (double)T_*mean*mean) / (double)(T_-1);
    if (var < 0.0) var = 0.0;
    double rstd = 1.0/(sqrt(var) + 1e-8);
    g_stats[b*2] = mean; g_stats[b*2+1] = rstd;
  }
}

// ---------------- harmonic additive synth (phase scan fused) ----------------
__global__ __launch_bounds__(256) void k_signal(const float* __restrict__ amps,
                                                const float* __restrict__ goq){
  __shared__ __align__(16) float As[TT_*100];
  __shared__ float ph[TT_];
  int b = blockIdx.x / NCH, c = blockIdx.x % NCH;
  int t0 = c*TT_;
  int tid = threadIdx.x;
  // wave 0: 64-lane inclusive f64 scan of dp + chunk offset
  if (tid < 64){
    int idx = b*T_ + t0 + tid;
    double v = g_dp[idx];
    for (int o=1;o<64;o<<=1){ double u = __shfl_up(v, o); if (tid >= o) v += u; }
    double fund = g_chunkoff[b*NCH + c] + v;
    ph[tid] = (float)fmod(fund, TWO_PI_D);
  }
  const float4* ag = (const float4*)(amps + ((size_t)b*T_ + t0)*H_);
  for (int i4 = tid; i4 < TT_*H_/4; i4 += 256){
    int row = i4 / 24, col4 = i4 - row*24;
    float4 v = ag[i4];
    *((float4*)&As[row*100 + col4*4]) = v;
  }
  __syncthreads();
  int tl = tid >> 2, part = tid & 3;
  int idx = b*T_ + t0 + tl;
  float r = ph[tl];
  int hc = (int)g_hcnt[idx];
  float oq = goq[idx];
  float k1 = 1.57079632679f / oq;
  float k2 = 1.57079632679f / (1.0f - oq);
  float sum = 0.f;
  const float4* Ar = (const float4*)&As[tl*100 + part*24];
  #pragma unroll
  for (int j4=0;j4<6;j4++){
    float4 a4 = Ar[j4];
    float av0[4] = {a4.x, a4.y, a4.z, a4.w};
    #pragma unroll
    for (int e=0;e<4;e++){
      int h = part*24 + j4*4 + e;
      float nn = (float)(h+1);
      float amp = (h < hc) ? av0[e] : 0.0f;
      float fr = r * nn * 0.15915494309189535f;
      fr = fr - floorf(fr);
      float a1 = fr * k1;
      float a2 = (fr - oq) * k2;
      float s = __sinf(a1);
      float cc = __cosf(a2);
      float v = (fr < oq) ? s*s : cc*cc;
      sum = fmaf(v - 0.5f, amp, sum);
    }
  }
  sum += __shfl_xor(sum, 1);
  sum += __shfl_xor(sum, 2);
  if (part == 0) g_signal[idx] = sum;
}

// ---------------- FFT: N = 64000 = 512 * 125 ----------------
template<int SGN>
__device__ __forceinline__ float2* fft512_stages(float2* bufA, float2* bufB, int tid){
  float2* src = bufA; float2* dst = bufB;
  #pragma unroll
  for (int st=0; st<9; st++){
    const int s = 1<<st;
    const int n = 512>>st;
    const int m = n>>1;
    int p = tid >> st;
    int q = tid & (s-1);
    float2 a  = src[q + s*p];
    float2 bb = src[q + s*(p+m)];
    float ang = (float)SGN * ((float)(2.0*M_PI)/(float)n) * (float)p;
    float sw, cw; __sincosf(ang, &sw, &cw);
    dst[q + 2*s*p]     = cadd(a, bb);
    dst[q + 2*s*p + s] = cmul(make_float2(cw, sw), csub(a, bb));
    __syncthreads();
    float2* tp = src; src = dst; dst = tp;
  }
  return src;
}

__device__ __forceinline__ cplx w5k(int k, float sgn){
  const float C[5] = {1.f, 0.30901699f, -0.80901699f, -0.80901699f, 0.30901699f};
  const float S[5] = {0.f, 0.95105652f, 0.58778525f, -0.58778525f, -0.95105652f};
  return make_float2(C[k], sgn*S[k]);
}

template<int SGN>
__device__ __forceinline__ float2* fft125_rows(float2* bufA, float2* bufB, int tid){
  float2* src = bufA; float2* dst = bufB;
  #pragma unroll
  for (int st=0; st<3; st++){
    const int s = (st==0)?1:((st==1)?5:25);
    const int n = (st==0)?125:((st==1)?25:5);
    const int m = n/5;
    if (tid < 200){
      int row = tid/25, w = tid - row*25;
      int p = w/s, q = w - p*s;
      int base = row*125 + q;
      float2 a0 = src[base + s*p];
      float2 a1 = src[base + s*(p+m)];
      float2 a2 = src[base + s*(p+2*m)];
      float2 a3 = src[base + s*(p+3*m)];
      float2 a4 = src[base + s*(p+4*m)];
      #pragma unroll
      for (int r2=0;r2<5;r2++){
        float2 acc = a0;
        acc = cadd(acc, cmul(a1, w5k((1*r2)%5, (float)SGN)));
        acc = cadd(acc, cmul(a2, w5k((2*r2)%5, (float)SGN)));
        acc = cadd(acc, cmul(a3, w5k((3*r2)%5, (float)SGN)));
        acc = cadd(acc, cmul(a4, w5k((4*r2)%5, (float)SGN)));
        float ang = (float)SGN * ((float)(2.0*M_PI)/(float)n) * (float)(p*r2);
        float sw,cw; __sincosf(ang,&sw,&cw);
        dst[base + s*(5*p+r2)] = cmul(make_float2(cw,sw), acc);
      }
    }
    __syncthreads();
    float2* tp = src; src = dst; dst = tp;
  }
  return src;
}

__global__ __launch_bounds__(256) void k_fft512_fwd(){
  int b = blockIdx.x / 125, n1 = blockIdx.x % 125;
  int tid = threadIdx.x;
  __shared__ float2 bufA[512];
  __shared__ float2 bufB[512];
  for (int i=tid;i<512;i+=256) bufA[i] = make_float2(g_signal[b*T_ + n1 + 125*i], 0.f);
  __syncthreads();
  float2* res = fft512_stages<-1>(bufA, bufB, tid);
  for (int i=tid;i<512;i+=256){
    float ang = -(float)(2.0*M_PI/64000.0) * (float)(n1*i);
    float sw,cw; __sincosf(ang,&sw,&cw);
    g_W1[((size_t)b*512 + i)*125 + n1] = cmul(make_float2(cw,sw), res[i]);
  }
}

__global__ __launch_bounds__(256) void k_fft125_mid(const float* __restrict__ ffq,
                                                    const float* __restrict__ fbw,
                                                    const float* __restrict__ fgn){
  int b = blockIdx.x / 64;
  int k2base = (blockIdx.x % 64) * 8;
  int tid = threadIdx.x;
  __shared__ float2 bufA[1000];
  __shared__ float2 bufB[1000];
  const float2* gin = g_W1 + ((size_t)b*512 + k2base)*125;
  for (int i=tid;i<1000;i+=256) bufA[i] = gin[i];
  float fcv[4], bwv[4], gv[4];
  #pragma unroll
  for (int j=0;j<4;j++){
    size_t base = ((size_t)b*T_ + T_/2)*4 + j;
    fcv[j] = ffq[base]; bwv[j] = fbw[base]; gv[j] = fgn[base];
  }
  __syncthreads();
  float2* res = fft125_rows<-1>(bufA, bufB, tid);
  for (int i=tid;i<1000;i+=256){
    int row = i/125, kk1 = i - row*125;
    int f = (k2base+row) + 512*kk1;
    int fi = (f <= 32000) ? f : (64000 - f);
    float freq = (float)fi * 0.6890625f;
    float resp = 0.f;
    #pragma unroll
    for (int j=0;j<4;j++){
      float dd = (freq - fcv[j]) / (bwv[j]*0.5f);
      resp += gv[j] / (1.0f + dd*dd);
    }
    res[i] = make_float2(res[i].x*resp, res[i].y*resp);
  }
  __syncthreads();
  float2* other = (res == bufA) ? bufB : bufA;
  float2* res2 = fft125_rows<1>(res, other, tid);
  for (int i=tid;i<1000;i+=256){
    int row = i/125, n1 = i - row*125;
    int k2 = k2base + row;
    float ang = (float)(2.0*M_PI/64000.0) * (float)(n1*k2);
    float sw,cw; __sincosf(ang,&sw,&cw);
    g_Z[((size_t)b*125 + n1)*512 + k2] = cmul(make_float2(cw,sw), res2[i]);
  }
}

__global__ __launch_bounds__(256) void k_fft512_inv(const float* __restrict__ brth,
                                                    float* __restrict__ outp){
  int b = blockIdx.x / 125, n1 = blockIdx.x % 125;
  int tid = threadIdx.x;
  __shared__ float2 bufA[512];
  __shared__ float2 bufB[512];
  const float2* gin = g_Z + ((size_t)b*125 + n1)*512;
  for (int i=tid;i<512;i+=256) bufA[i] = gin[i];
  __syncthreads();
  float2* res = fft512_stages<1>(bufA, bufB, tid);
  float mean = (float)g_stats[b*2], rstd = (float)g_stats[b*2+1];
  for (int i=tid;i<512;i+=256){
    int t = n1 + 125*i;
    int idx = b*T_ + t;
    float filt = res[i].x * (1.0f/64000.0f);
    float br = brth[idx];
    float breath = (g_shaped[idx] - mean) * rstd;
    outp[idx] = filt*(1.0f - br) + breath*br;
  }
}

extern "C" void kernel_launch(void* const* d_in, const int* in_sizes, int n_in,
                              void* d_out, int out_size, void* d_ws, size_t ws_size,
                              hipStream_t stream){
  (void)in_sizes; (void)n_in; (void)out_size; (void)d_ws; (void)ws_size;
  const float* f0   = (const float*)d_in[0];
  const float* amps = (const float*)d_in[1];
  const float* vr   = (const float*)d_in[2];
  const float* vd   = (const float*)d_in[3];
  const float* ffq  = (const float*)d_in[4];
  const float* fbw  = (const float*)d_in[5];
  const float* fgn  = (const float*)d_in[6];
  const float* goq  = (const float*)d_in[7];
  const float* brth = (const float*)d_in[9];
  const float* bss  = (const float*)d_in[10];
  const float* iph  = (const float*)d_in[11];
  float* out = (float*)d_out;

  k_breath<<<B_*250,256,0,stream>>>(bss);
  k_chunksum<<<B_*250,256,0,stream>>>(f0, vr, vd);
  k_scanstats<<<B_,256,0,stream>>>(iph, out + (size_t)B_*T_);
  k_signal<<<B_*NCH,256,0,stream>>>(amps, goq);
  k_fft512_fwd<<<500,256,0,stream>>>();
  k_fft125_mid<<<256,256,0,stream>>>(ffq, fbw, fgn);
  k_fft512_inv<<<500,256,0,stream>>>(brth, out);
}

// Round 9
// 80.602 us; speedup vs baseline: 1.9784x; 1.0424x over previous
//
#include <hip/hip_runtime.h>
#include <math.h>
#include <stdint.h>

#define B_ 4
#define T_ 64000
#define H_ 96
#define NCH 1000
#define TT_ 64
#define TWO_PI_D 6.283185307179586

typedef float2 cplx;
__device__ __forceinline__ cplx cadd(cplx a, cplx b){ return make_float2(a.x+b.x, a.y+b.y); }
__device__ __forceinline__ cplx csub(cplx a, cplx b){ return make_float2(a.x-b.x, a.y-b.y); }
__device__ __forceinline__ cplx cmul(cplx a, cplx b){ return make_float2(a.x*b.x - a.y*b.y, a.x*b.y + a.y*b.x); }

// ---------------- static scratch ----------------
__device__ double g_dp[B_*T_];
__device__ unsigned char g_hcnt[B_*T_];
__device__ float  g_signal[B_*T_];
__device__ float  g_shaped[B_*T_];
__device__ float2 g_W1[2*512*125];
__device__ float2 g_Z[2*125*512];
__device__ double g_chunksum[B_*NCH];
__device__ double g_chunkoff[B_*NCH];
__device__ double g_stats[B_*2];
__device__ double g_part[B_*250*2];

// ---------------- threefry (partitionable, out0^out1) ----------------
__device__ __forceinline__ uint32_t rotl32(uint32_t x, int r){ return (x<<r)|(x>>(32-r)); }

__device__ __forceinline__ uint32_t threefry_bits(uint32_t i){
  uint32_t x0 = 0u, x1 = i;
  const uint32_t ks0 = 0u, ks1 = 42u, ks2 = 0u ^ 42u ^ 0x1BD11BDAu;
  x0 += ks0; x1 += ks1;
  #define TFR(r) { x0 += x1; x1 = rotl32(x1, r); x1 ^= x0; }
  TFR(13) TFR(15) TFR(26) TFR(6)   x0 += ks1; x1 += ks2 + 1u;
  TFR(17) TFR(29) TFR(16) TFR(24)  x0 += ks2; x1 += ks0 + 2u;
  TFR(13) TFR(15) TFR(26) TFR(6)   x0 += ks0; x1 += ks1 + 3u;
  TFR(17) TFR(29) TFR(16) TFR(24)  x0 += ks1; x1 += ks2 + 4u;
  TFR(13) TFR(15) TFR(26) TFR(6)   x0 += ks2; x1 += ks0 + 5u;
  #undef TFR
  return x0 ^ x1;
}

__device__ __forceinline__ float bits_to_normal(uint32_t bits){
  uint32_t mbits = (bits >> 9) | 0x3F800000u;
  float f = __uint_as_float(mbits) - 1.0f;
  const float lo = -0.99999994f;
  float x = f * 2.0f + lo;
  x = fmaxf(lo, x);
  float w = -log1pf(-x*x);
  float p;
  if (w < 5.0f){
    w -= 2.5f;
    p = 2.81022636e-08f;
    p = fmaf(p, w, 3.43273939e-07f);
    p = fmaf(p, w, -3.5233877e-06f);
    p = fmaf(p, w, -4.39150654e-06f);
    p = fmaf(p, w, 0.00021858087f);
    p = fmaf(p, w, -0.00125372503f);
    p = fmaf(p, w, -0.00417768164f);
    p = fmaf(p, w, 0.246640727f);
    p = fmaf(p, w, 1.50140941f);
  } else {
    w = sqrtf(w) - 3.0f;
    p = -0.000200214257f;
    p = fmaf(p, w, 0.000100950558f);
    p = fmaf(p, w, 0.00134934322f);
    p = fmaf(p, w, -0.00367342844f);
    p = fmaf(p, w, 0.00573950773f);
    p = fmaf(p, w, -0.0076224613f);
    p = fmaf(p, w, 0.00943887047f);
    p = fmaf(p, w, 1.00167406f);
    p = fmaf(p, w, 2.83297682f);
  }
  return 1.4142135623730951f * (p * x);
}

__constant__ int KSZc[8] = {129,91,65,45,33,23,17,11};

// ---------------- prep: breath(noise+kern+conv+stats partial) + phase increments ----------------
__global__ __launch_bounds__(256) void k_prep(const float* __restrict__ bss,
                                              const float* __restrict__ f0,
                                              const float* __restrict__ vr,
                                              const float* __restrict__ vd){
  int b = blockIdx.x / 250, c = blockIdx.x % 250;
  int t0 = c*256, tid = threadIdx.x;
  // ---- breath part ----
  __shared__ float ns[384];
  __shared__ float kl[129];
  __shared__ float wn[8];
  if (tid < 8){
    int ksz = KSZc[tid];
    float sig = (float)ksz / 6.0f;
    float inv2s2 = 1.0f/(2.0f*sig*sig);
    int ctr = ksz>>1;
    float s = 0.f;
    for (int j=0;j<ksz;j++){ float d = (float)(j - ctr); s += expf(-d*d*inv2s2); }
    wn[tid] = bss[((size_t)b*T_ + T_/2)*8 + tid] / s;
  }
  for (int j = tid; j < 384; j += 256){
    int t = t0 - 64 + j;
    float v = 0.f;
    if (t >= 0 && t < T_) v = bits_to_normal(threefry_bits((uint32_t)(b*T_ + t)));
    ns[j] = v;
  }
  __syncthreads();
  if (tid < 129){
    int tau = tid - 64;
    float acc = 0.f;
    #pragma unroll
    for (int i=0;i<8;i++){
      int ksz = KSZc[i]; int hw = ksz>>1;
      if (tau >= -hw && tau <= hw){
        float sig = (float)ksz/6.0f;
        float inv2s2 = 1.0f/(2.0f*sig*sig);
        acc += expf(-(float)(tau*tau)*inv2s2) * wn[i];
      }
    }
    kl[tid] = acc;
  }
  __syncthreads();
  float acc = 0.f;
  for (int j=0;j<129;j++) acc = fmaf(ns[tid+j], kl[j], acc);
  g_shaped[b*T_ + t0 + tid] = acc;
  double xx = (double)acc;
  double s1 = xx, s2 = xx*xx;
  for (int o=1;o<64;o<<=1){ s1 += __shfl_down(s1,o); s2 += __shfl_down(s2,o); }
  __shared__ double a1[4], a2[4];
  int lane = tid&63, wid = tid>>6;
  if (lane==0){ a1[wid]=s1; a2[wid]=s2; }
  __syncthreads();
  if (tid==0){
    g_part[(b*250+c)*2]   = a1[0]+a1[1]+a1[2]+a1[3];
    g_part[(b*250+c)*2+1] = a2[0]+a2[1]+a2[2]+a2[3];
  }
  // ---- phase increments + harmonic count + 64-chunk sums ----
  int t = t0 + tid;
  int idx = b*T_ + t;
  double tt = (double)t / 44100.0;
  double sv = sin(TWO_PI_D * (double)vr[idx] * tt);
  double lm = (double)vd[idx] * 0.057762265046662105;   // ln2/12
  double vm = exp(sv * lm);
  double f0s = (double)f0[idx];
  double f0v = (f0s > 0.0) ? f0s * vm : f0s;
  int cnt = 0;
  #pragma unroll
  for (int n=1;n<=96;n++) cnt += ((double)n * f0v < 22050.0) ? 1 : 0;
  g_hcnt[idx] = (unsigned char)cnt;
  double v = TWO_PI_D * f0v / 44100.0;
  g_dp[idx] = v;
  for (int o=1;o<64;o<<=1) v += __shfl_down(v, o);
  if (lane == 0) g_chunksum[b*NCH + c*4 + wid] = v;
}

// ---------------- scan 1000 chunks/batch + final phase + stats finish ----------------
__global__ __launch_bounds__(256) void k_scanstats(const float* __restrict__ iph,
                                                   float* __restrict__ out_final){
  int b = blockIdx.x;
  int tid = threadIdx.x;
  __shared__ double sc[256];
  double v0[4];
  double s = 0.0;
  #pragma unroll
  for (int k=0;k<4;k++){
    int ch = tid*4 + k;
    double x = (ch < NCH) ? g_chunksum[b*NCH+ch] : 0.0;
    v0[k] = x; s += x;
  }
  sc[tid] = s;
  __syncthreads();
  for (int off=1; off<256; off<<=1){
    double u = (tid>=off) ? sc[tid-off] : 0.0;
    __syncthreads();
    sc[tid] += u;
    __syncthreads();
  }
  double init = (double)iph[b];
  double excl = ((tid==0) ? 0.0 : sc[tid-1]) + init;
  #pragma unroll
  for (int k=0;k<4;k++){
    int ch = tid*4 + k;
    if (ch < NCH) g_chunkoff[b*NCH+ch] = excl;
    excl += v0[k];
  }
  if (tid == 255) out_final[b] = (float)fmod(sc[255] + init, TWO_PI_D);
  double s1=0.0, s2=0.0;
  if (tid < 250){ s1 = g_part[(b*250+tid)*2]; s2 = g_part[(b*250+tid)*2+1]; }
  for (int o=1;o<64;o<<=1){ s1 += __shfl_down(s1,o); s2 += __shfl_down(s2,o); }
  __shared__ double a1[4], a2[4];
  int lane = tid&63, wid = tid>>6;
  if (lane==0){ a1[wid]=s1; a2[wid]=s2; }
  __syncthreads();
  if (tid==0){
    double S1=a1[0]+a1[1]+a1[2]+a1[3], S2=a2[0]+a2[1]+a2[2]+a2[3];
    double mean = S1 / (double)T_;
    double var = (S2 - (double)T_*mean*mean) / (double)(T_-1);
    if (var < 0.0) var = 0.0;
    double rstd = 1.0/(sqrt(var) + 1e-8);
    g_stats[b*2] = mean; g_stats[b*2+1] = rstd;
  }
}

// ---------------- harmonic additive synth (phase scan fused) ----------------
__global__ __launch_bounds__(256) void k_signal(const float* __restrict__ amps,
                                                const float* __restrict__ goq){
  __shared__ __align__(16) float As[TT_*100];
  __shared__ float ph[TT_];
  int b = blockIdx.x / NCH, c = blockIdx.x % NCH;
  int t0 = c*TT_;
  int tid = threadIdx.x;
  if (tid < 64){
    int idx = b*T_ + t0 + tid;
    double v = g_dp[idx];
    for (int o=1;o<64;o<<=1){ double u = __shfl_up(v, o); if (tid >= o) v += u; }
    double fund = g_chunkoff[b*NCH + c] + v;
    ph[tid] = (float)fmod(fund, TWO_PI_D);
  }
  const float4* ag = (const float4*)(amps + ((size_t)b*T_ + t0)*H_);
  for (int i4 = tid; i4 < TT_*H_/4; i4 += 256){
    int row = i4 / 24, col4 = i4 - row*24;
    float4 v = ag[i4];
    *((float4*)&As[row*100 + col4*4]) = v;
  }
  __syncthreads();
  int tl = tid >> 2, part = tid & 3;
  int idx = b*T_ + t0 + tl;
  float r = ph[tl];
  int hc = (int)g_hcnt[idx];
  float oq = goq[idx];
  float k1 = 1.57079632679f / oq;
  float k2 = 1.57079632679f / (1.0f - oq);
  float sum = 0.f;
  const float4* Ar = (const float4*)&As[tl*100 + part*24];
  #pragma unroll
  for (int j4=0;j4<6;j4++){
    float4 a4 = Ar[j4];
    float av0[4] = {a4.x, a4.y, a4.z, a4.w};
    #pragma unroll
    for (int e=0;e<4;e++){
      int h = part*24 + j4*4 + e;
      float nn = (float)(h+1);
      float amp = (h < hc) ? av0[e] : 0.0f;
      float fr = r * nn * 0.15915494309189535f;
      fr = fr - floorf(fr);
      float a1 = fr * k1;
      float a2 = (fr - oq) * k2;
      float s = __sinf(a1);
      float cc = __cosf(a2);
      float v = (fr < oq) ? s*s : cc*cc;
      sum = fmaf(v - 0.5f, amp, sum);
    }
  }
  sum += __shfl_xor(sum, 1);
  sum += __shfl_xor(sum, 2);
  if (part == 0) g_signal[idx] = sum;
}

// ---------------- FFT: N = 64000 = 512*125, batch-pairs packed real+imag ----------------
template<int SGN>
__device__ __forceinline__ float2* fft512_stages(float2* bufA, float2* bufB, int tid){
  float2* src = bufA; float2* dst = bufB;
  #pragma unroll
  for (int st=0; st<9; st++){
    const int s = 1<<st;
    const int n = 512>>st;
    const int m = n>>1;
    int p = tid >> st;
    int q = tid & (s-1);
    float2 a  = src[q + s*p];
    float2 bb = src[q + s*(p+m)];
    float ang = (float)SGN * ((float)(2.0*M_PI)/(float)n) * (float)p;
    float sw, cw; __sincosf(ang, &sw, &cw);
    dst[q + 2*s*p]     = cadd(a, bb);
    dst[q + 2*s*p + s] = cmul(make_float2(cw, sw), csub(a, bb));
    __syncthreads();
    float2* tp = src; src = dst; dst = tp;
  }
  return src;
}

__device__ __forceinline__ cplx w5k(int k, float sgn){
  const float C[5] = {1.f, 0.30901699f, -0.80901699f, -0.80901699f, 0.30901699f};
  const float S[5] = {0.f, 0.95105652f, 0.58778525f, -0.58778525f, -0.95105652f};
  return make_float2(C[k], sgn*S[k]);
}

template<int SGN>
__device__ __forceinline__ float2* fft125_rows(float2* bufA, float2* bufB, int tid){
  float2* src = bufA; float2* dst = bufB;
  #pragma unroll
  for (int st=0; st<3; st++){
    const int s = (st==0)?1:((st==1)?5:25);
    const int n = (st==0)?125:((st==1)?25:5);
    const int m = n/5;
    if (tid < 200){
      int row = tid/25, w = tid - row*25;
      int p = w/s, q = w - p*s;
      int base = row*125 + q;
      float2 a0 = src[base + s*p];
      float2 a1 = src[base + s*(p+m)];
      float2 a2 = src[base + s*(p+2*m)];
      float2 a3 = src[base + s*(p+3*m)];
      float2 a4 = src[base + s*(p+4*m)];
      #pragma unroll
      for (int r2=0;r2<5;r2++){
        float2 acc = a0;
        acc = cadd(acc, cmul(a1, w5k((1*r2)%5, (float)SGN)));
        acc = cadd(acc, cmul(a2, w5k((2*r2)%5, (float)SGN)));
        acc = cadd(acc, cmul(a3, w5k((3*r2)%5, (float)SGN)));
        acc = cadd(acc, cmul(a4, w5k((4*r2)%5, (float)SGN)));
        float ang = (float)SGN * ((float)(2.0*M_PI)/(float)n) * (float)(p*r2);
        float sw,cw; __sincosf(ang,&sw,&cw);
        dst[base + s*(5*p+r2)] = cmul(make_float2(cw,sw), acc);
      }
    }
    __syncthreads();
    float2* tp = src; src = dst; dst = tp;
  }
  return src;
}

__global__ __launch_bounds__(256) void k_fft512_fwd(){
  int p = blockIdx.x / 125, n1 = blockIdx.x % 125;
  int tid = threadIdx.x;
  __shared__ float2 bufA[512];
  __shared__ float2 bufB[512];
  const float* sa = g_signal + (size_t)(2*p)*T_;
  const float* sb = g_signal + (size_t)(2*p+1)*T_;
  for (int i=tid;i<512;i+=256) bufA[i] = make_float2(sa[n1 + 125*i], sb[n1 + 125*i]);
  __syncthreads();
  float2* res = fft512_stages<-1>(bufA, bufB, tid);
  for (int i=tid;i<512;i+=256){
    float ang = -(float)(2.0*M_PI/64000.0) * (float)(n1*i);
    float sw,cw; __sincosf(ang,&sw,&cw);
    g_W1[((size_t)p*512 + i)*125 + n1] = cmul(make_float2(cw,sw), res[i]);
  }
}

__global__ __launch_bounds__(256) void k_fft125_mid(const float* __restrict__ ffq,
                                                    const float* __restrict__ fbw,
                                                    const float* __restrict__ fgn){
  int p = blockIdx.x / 64;     // batch pair
  int j = blockIdx.x % 64;
  int tid = threadIdx.x;
  __shared__ float2 bufA[1000];
  __shared__ float2 bufB[1000];
  int k2r[8];
  #pragma unroll
  for (int l=0;l<8;l++){
    int k2;
    if (l < 4) k2 = 4*j + l;
    else if (j==0 && l==4) k2 = 256;
    else k2 = 512 - 4*j - (l-4);
    k2r[l] = k2;
  }
  for (int i=tid;i<1000;i+=256){
    int l = i/125, n1 = i - l*125;
    bufA[i] = g_W1[((size_t)p*512 + k2r[l])*125 + n1];
  }
  float fca[4], bwa[4], ga[4], fcb[4], bwb[4], gb[4];
  int ba = 2*p, bb = 2*p+1;
  #pragma unroll
  for (int q=0;q<4;q++){
    size_t ia = ((size_t)ba*T_ + T_/2)*4 + q;
    size_t ib = ((size_t)bb*T_ + T_/2)*4 + q;
    fca[q]=ffq[ia]; bwa[q]=fbw[ia]; ga[q]=fgn[ia];
    fcb[q]=ffq[ib]; bwb[q]=fbw[ib]; gb[q]=fgn[ib];
  }
  __syncthreads();
  float2* X = fft125_rows<-1>(bufA, bufB, tid);
  float2* Y = (X == bufA) ? bufB : bufA;
  for (int i=tid;i<1000;i+=256){
    int l = i/125, k1 = i - l*125;
    int k2 = k2r[l];
    int lm = ((j==0) && (l==0 || l==4)) ? l : (l^4);
    int k1m = (k2 == 0) ? ((k1==0)?0:(125-k1)) : (124-k1);
    float2 Z1 = X[l*125 + k1];
    float2 Z2 = X[lm*125 + k1m];
    float xax = 0.5f*(Z1.x + Z2.x), xay = 0.5f*(Z1.y - Z2.y);
    float xbx = 0.5f*(Z1.y + Z2.y), xby = -0.5f*(Z1.x - Z2.x);
    int f = k2 + 512*k1;
    int fi = (f <= 32000) ? f : (64000 - f);
    float freq = (float)fi * 0.6890625f;
    float ra = 0.f, rb = 0.f;
    #pragma unroll
    for (int q=0;q<4;q++){
      float da = (freq - fca[q]) / (bwa[q]*0.5f);
      ra += ga[q] / (1.0f + da*da);
      float db = (freq - fcb[q]) / (bwb[q]*0.5f);
      rb += gb[q] / (1.0f + db*db);
    }
    float yax = ra*xax, yay = ra*xay;
    float ybx = rb*xbx, yby = rb*xby;
    Y[i] = make_float2(yax - yby, yay + ybx);   // V = Ya + i*Yb
  }
  __syncthreads();
  float2* res2 = fft125_rows<1>(Y, X, tid);
  for (int i=tid;i<1000;i+=256){
    int l = i/125, n1 = i - l*125;
    int k2 = k2r[l];
    float ang = (float)(2.0*M_PI/64000.0) * (float)(n1*k2);
    float sw,cw; __sincosf(ang,&sw,&cw);
    g_Z[((size_t)p*125 + n1)*512 + k2] = cmul(make_float2(cw,sw), res2[i]);
  }
}

__global__ __launch_bounds__(256) void k_fft512_inv(const float* __restrict__ brth,
                                                    float* __restrict__ outp){
  int p = blockIdx.x / 125, n1 = blockIdx.x % 125;
  int tid = threadIdx.x;
  __shared__ float2 bufA[512];
  __shared__ float2 bufB[512];
  const float2* gin = g_Z + ((size_t)p*125 + n1)*512;
  for (int i=tid;i<512;i+=256) bufA[i] = gin[i];
  __syncthreads();
  float2* res = fft512_stages<1>(bufA, bufB, tid);
  int ba = 2*p, bb = 2*p+1;
  float mean_a = (float)g_stats[ba*2], rstd_a = (float)g_stats[ba*2+1];
  float mean_b = (float)g_stats[bb*2], rstd_b = (float)g_stats[bb*2+1];
  for (int i=tid;i<512;i+=256){
    int t = n1 + 125*i;
    float2 v = res[i];
    {
      int idx = ba*T_ + t;
      float filt = v.x * (1.0f/64000.0f);
      float br = brth[idx];
      float breath = (g_shaped[idx] - mean_a) * rstd_a;
      outp[idx] = filt*(1.0f - br) + breath*br;
    }
    {
      int idx = bb*T_ + t;
      float filt = v.y * (1.0f/64000.0f);
      float br = brth[idx];
      float breath = (g_shaped[idx] - mean_b) * rstd_b;
      outp[idx] = filt*(1.0f - br) + breath*br;
    }
  }
}

extern "C" void kernel_launch(void* const* d_in, const int* in_sizes, int n_in,
                              void* d_out, int out_size, void* d_ws, size_t ws_size,
                              hipStream_t stream){
  (void)in_sizes; (void)n_in; (void)out_size; (void)d_ws; (void)ws_size;
  const float* f0   = (const float*)d_in[0];
  const float* amps = (const float*)d_in[1];
  const float* vr   = (const float*)d_in[2];
  const float* vd   = (const float*)d_in[3];
  const float* ffq  = (const float*)d_in[4];
  const float* fbw  = (const float*)d_in[5];
  const float* fgn  = (const float*)d_in[6];
  const float* goq  = (const float*)d_in[7];
  const float* brth = (const float*)d_in[9];
  const float* bss  = (const float*)d_in[10];
  const float* iph  = (const float*)d_in[11];
  float* out = (float*)d_out;

  k_prep<<<B_*250,256,0,stream>>>(bss, f0, vr, vd);
  k_scanstats<<<B_,256,0,stream>>>(iph, out + (size_t)B_*T_);
  k_signal<<<B_*NCH,256,0,stream>>>(amps, goq);
  k_fft512_fwd<<<250,256,0,stream>>>();
  k_fft125_mid<<<128,256,0,stream>>>(ffq, fbw, fgn);
  k_fft512_inv<<<250,256,0,stream>>>(brth, out);
}